// Round 13
// baseline (1153.048 us; speedup 1.0000x reference)
//
#include <hip/hip_runtime.h>
#include <hip/hip_bf16.h>

// GraphConvLayer: out = relu(A_norm @ (X@W + b))
// R13 = R12 (dense two-GEMM MFMA) + software pipeline on GEMM1's K-loop:
//  - chunk c+1 reg-staged (32 f32 + uint4) while chunk c MFMAs
//  - raw s_barrier + manual lgkmcnt(0) in the K-loop (no vmcnt drain -> loads
//    stay in flight across barriers; __syncthreads would drain them)
//   GEMM1: Y[64][256] = A_tile[64][543] @ X_bt[543][256]   (K-chunks of 64)
//   GEMM2: out = relu(Y @ W + rowsum(A)*b)

#define NND    543
#define RPB    64           // output rows per block
#define NTILES 9            // tiles per bt
#define NCH    9            // K chunks of 64
#define BTOT   1024
#define GRID   (BTOT*NTILES)   // 9216, %8==0 -> bijective XCD swizzle

typedef __attribute__((ext_vector_type(8))) short short8;
typedef __attribute__((ext_vector_type(4))) float f32x4;

// ---- workspace (bytes) ----
#define WS_A   0                          // bf16 A-frags [tile9][chunk9][f8][lane64][8] = 663552
#define WS_W   663552                     // bf16 W-frags [g16][ks8][lane64][8] = 131072
#define WS_RS  794624                     // f32[576] rowsum (padded)
#define WS_NEED 796928

// ---- LDS (bytes) ----
#define L_XT   0            // Xt bf16 [256 n][128B k-swz] = 32768; Y-swz + bounce overlay later
#define L_A    32768        // A-frag stage [8 frags][64 lanes][16B] = 8192
#define L_RS   40960        // f32[64]
#define L_TOT  41216        // 40.3 KB

__device__ __forceinline__ unsigned short f2bf(float f) {   // RNE f32 -> bf16 bits
  unsigned int u = __builtin_bit_cast(unsigned int, f);
  u += 0x7fffu + ((u >> 16) & 1u);
  return (unsigned short)(u >> 16);
}

// ---------------- prep: A -> bf16 MFMA A-fragments ----------------
// frag f = mt*2+ks; element e: m = tile*64 + mt*16 + (lane&15),
//                              k = chunk*64 + ks*32 + (lane>>4)*8 + e
__global__ void prep_a(const float* __restrict__ A, char* __restrict__ ws) {
  const int t = blockIdx.x * 256 + threadIdx.x;
  if (t >= NTILES * NCH * 8 * 64) return;
  const int lane = t & 63;
  const int f = (t >> 6) & 7;
  const int c = (t >> 9) % NCH;
  const int tile = t / (NCH * 8 * 64);
  const int mt = f >> 1, ks = f & 1;
  const int m = tile * 64 + mt * 16 + (lane & 15);
  const int kb = c * 64 + ks * 32 + (lane >> 4) * 8;
  unsigned short* dst = (unsigned short*)(ws + WS_A) + (size_t)t * 8;
  #pragma unroll
  for (int e = 0; e < 8; ++e) {
    const int k = kb + e;
    dst[e] = (m < NND && k < NND) ? f2bf(A[(size_t)m * NND + k]) : (unsigned short)0;
  }
}

// ---------------- prep: W -> bf16 MFMA B-fragments [g][ks][lane][8], g = col/16 ----------------
__global__ void prep_w(const float* __restrict__ W, char* __restrict__ ws) {
  const int t = blockIdx.x * 256 + threadIdx.x;
  if (t >= 16 * 8 * 64) return;
  const int lane = t & 63, ks = (t >> 6) & 7, g = t >> 9;
  const int krow = (lane >> 4) * 8, col = g * 16 + (lane & 15);
  unsigned short* dst = (unsigned short*)(ws + WS_W) + (size_t)t * 8;
  #pragma unroll
  for (int e = 0; e < 8; e++) dst[e] = f2bf(W[(ks * 32 + krow + e) * 256 + col]);
}

// ---------------- prep: rowsum (one wave per row) ----------------
__global__ void prep_rs(const float* __restrict__ A, char* __restrict__ ws) {
  const int wid = (blockIdx.x * blockDim.x + threadIdx.x) >> 6;
  const int lane = threadIdx.x & 63;
  if (wid >= NTILES * RPB) return;
  float s = 0.f;
  if (wid < NND) {
    const float* arow = A + (size_t)wid * NND;
    for (int m = lane; m < NND; m += 64) s += arow[m];
  }
  #pragma unroll
  for (int o = 32; o > 0; o >>= 1) s += __shfl_xor(s, o);
  if (lane == 0) ((float*)(ws + WS_RS))[wid] = s;
}

// ---------------- main ----------------
__global__ __launch_bounds__(512, 2)   // 128 VGPR cap; LDS 40.3KB
void gcn_main(const float* __restrict__ x, const float* __restrict__ Wm,
              const float* __restrict__ bias, const float* __restrict__ A,
              float* __restrict__ out, const char* __restrict__ ws, int use_ws)
{
  __shared__ __align__(16) char lds[L_TOT];
  float* rsl = (float*)(lds + L_RS);

  const int tid = threadIdx.x;
  const int w = tid >> 6, lane = tid & 63;
  const int cl = lane & 15, krow = (lane >> 4) * 8;

  // XCD swizzle: the 9 tiles of one bt adjacent -> co-resident on one XCD
  const int p = blockIdx.x;
  const int L = (p & 7) * (GRID / 8) + (p >> 3);
  const int bt = L / NTILES;
  const int tile = L - bt * NTILES;
  const int n0 = tile * RPB;

  const float* xbt = x + (size_t)bt * (NND * 256);

  if (use_ws) {
    if (tid < RPB) rsl[tid] = ((const float*)(ws + WS_RS))[n0 + tid];

    // ======== GEMM1: Y = A_tile @ X, pipelined K-chunks of 64 ========
    f32x4 acc[8];                         // [mt*2+nt], static indices only
    #pragma unroll
    for (int i = 0; i < 8; ++i) acc[i] = (f32x4){0.f, 0.f, 0.f, 0.f};

    f32x4 xs[8];                          // staged chunk (32 VGPR), static via unroll
    uint4 av;                             // staged A-frag slice

    // prologue: issue chunk-0 loads
    #pragma unroll
    for (int it = 0; it < 8; ++it) {
      const int slot = tid + (it << 9);
      const int n = slot & 255, kb = (slot >> 8) << 2;   // chunk 0: kb+3 <= 63 < NND
      f32x4 v;
      v.x = xbt[(kb + 0) * 256 + n];
      v.y = xbt[(kb + 1) * 256 + n];
      v.z = xbt[(kb + 2) * 256 + n];
      v.w = xbt[(kb + 3) * 256 + n];
      xs[it] = v;
    }
    av = *(const uint4*)(ws + WS_A + ((size_t)((tile * NCH + 0) * 512 + tid) << 4));

    for (int c = 0; c < NCH; ++c) {
      // B1: all waves done MFMA-reading chunk c-1 (their ds_reads were consumed).
      // Raw barrier: does NOT drain vmcnt -> chunk-c loads may still be in flight
      // (compiler inserts the vmcnt waits right before xs use below).
      __builtin_amdgcn_s_barrier();
      __builtin_amdgcn_sched_barrier(0);

      // ---- pack + write chunk c to LDS ----
      #pragma unroll
      for (int it = 0; it < 8; ++it) {
        const int slot = tid + (it << 9);
        const int n = slot & 255, k0 = (slot >> 8) << 2;
        uint2 u;
        u.x = (unsigned)f2bf(xs[it].x) | ((unsigned)f2bf(xs[it].y) << 16);
        u.y = (unsigned)f2bf(xs[it].z) | ((unsigned)f2bf(xs[it].w) << 16);
        *(uint2*)(lds + L_XT + n * 128 + ((k0 * 2) ^ ((n & 7) << 4))) = u;
      }
      *(uint4*)(lds + L_A + (tid << 4)) = av;

      // ---- issue chunk c+1 loads (refill xs/av; in flight across the barrier) ----
      if (c + 1 < NCH) {
        const int cb = (c + 1) * 64;
        #pragma unroll
        for (int it = 0; it < 8; ++it) {
          const int slot = tid + (it << 9);
          const int n = slot & 255, kb = cb + ((slot >> 8) << 2);
          f32x4 v = (f32x4){0.f, 0.f, 0.f, 0.f};
          if (kb + 3 < NND) {             // wave-uniform branch
            v.x = xbt[(kb + 0) * 256 + n];
            v.y = xbt[(kb + 1) * 256 + n];
            v.z = xbt[(kb + 2) * 256 + n];
            v.w = xbt[(kb + 3) * 256 + n];
          } else {
            if (kb + 0 < NND) v.x = xbt[(kb + 0) * 256 + n];
            if (kb + 1 < NND) v.y = xbt[(kb + 1) * 256 + n];
            if (kb + 2 < NND) v.z = xbt[(kb + 2) * 256 + n];
            if (kb + 3 < NND) v.w = xbt[(kb + 3) * 256 + n];
          }
          xs[it] = v;
        }
        av = *(const uint4*)(ws + WS_A + ((size_t)((tile * NCH + c + 1) * 512 + tid) << 4));
      }

      // B2: chunk-c LDS writes visible to all waves (drain LDS only, not vmcnt)
      asm volatile("s_waitcnt lgkmcnt(0)" ::: "memory");
      __builtin_amdgcn_s_barrier();
      __builtin_amdgcn_sched_barrier(0);

      // ---- 16 MFMAs on chunk c ----
      #pragma unroll
      for (int ks = 0; ks < 2; ++ks) {
        short8 af[4], xf[2];
        #pragma unroll
        for (int mt = 0; mt < 4; ++mt)
          af[mt] = *(const short8*)(lds + L_A + (((mt * 2 + ks) * 64 + lane) << 4));
        #pragma unroll
        for (int nt = 0; nt < 2; ++nt) {
          const int n = w * 32 + nt * 16 + cl;
          xf[nt] = *(const short8*)(lds + L_XT + n * 128 +
                                    (((ks * 32 + krow) * 2) ^ ((n & 7) << 4)));
        }
        #pragma unroll
        for (int mt = 0; mt < 4; ++mt)
          #pragma unroll
          for (int nt = 0; nt < 2; ++nt)
            acc[mt * 2 + nt] =
                __builtin_amdgcn_mfma_f32_16x16x32_bf16(af[mt], xf[nt], acc[mt * 2 + nt], 0, 0, 0);
      }
    }

    // ---- Y -> LDS bf16 [64][512B] XOR-swz (overlays dead Xt) ----
    __syncthreads();
    #pragma unroll
    for (int mt = 0; mt < 4; ++mt) {
      #pragma unroll
      for (int nt = 0; nt < 2; ++nt) {
        #pragma unroll
        for (int q = 0; q < 4; ++q) {
          const int row = mt * 16 + (lane >> 4) * 4 + q;   // C/D: col=lane&15, row=(lane>>4)*4+q
          const int col = w * 32 + nt * 16 + cl;
          *(unsigned short*)(lds + L_XT + row * 512 + ((col * 2) ^ ((row & 7) << 4))) =
              f2bf(acc[mt * 2 + nt][q]);
        }
      }
    }
  } else {
    // ---- no-ws fallback: dense per-row f32 gather from global + rowsum ----
    for (int i = 0; i < 8; ++i) {
      const int r = w * 8 + i;
      const int n = n0 + r;
      f32x4 yv = (f32x4){0.f, 0.f, 0.f, 0.f};
      float s = 0.f;
      if (n < NND) {
        const float* arow = A + (size_t)n * NND;
        for (int m = 0; m < NND; ++m) {
          const float a = arow[m];
          s += a;
          if (a != 0.f) yv += a * *(const f32x4*)(xbt + (m << 8) + (lane << 2));
        }
      }
      if (lane == 0) rsl[r] = s;
      uint2 u;
      u.x = (unsigned)f2bf(yv.x) | ((unsigned)f2bf(yv.y) << 16);
      u.y = (unsigned)f2bf(yv.z) | ((unsigned)f2bf(yv.w) << 16);
      *(uint2*)(lds + L_XT + r * 512 + ((lane * 8) ^ ((r & 7) << 4))) = u;
    }
  }
  __syncthreads();

  // ======== GEMM2: out_tile = relu(Y@W + rs*b); wave w owns cols [w*32, w*32+32) ========
  const int gA = 2 * w;
  short8 wfA[8], wfB[8];
  if (use_ws) {
    #pragma unroll
    for (int ks = 0; ks < 8; ++ks) {
      wfA[ks] = *(const short8*)(ws + WS_W + (size_t)(((gA * 8 + ks) * 64 + lane) << 4));
      wfB[ks] = *(const short8*)(ws + WS_W + (size_t)((((gA + 1) * 8 + ks) * 64 + lane) << 4));
    }
  } else {
    #pragma unroll
    for (int ks = 0; ks < 8; ++ks) {
      #pragma unroll
      for (int e = 0; e < 8; ++e) {
        wfA[ks][e] = (short)f2bf(Wm[(ks * 32 + krow + e) * 256 + gA * 16 + cl]);
        wfB[ks][e] = (short)f2bf(Wm[(ks * 32 + krow + e) * 256 + (gA + 1) * 16 + cl]);
      }
    }
  }
  f32x4 accA[4], accB[4];
  #pragma unroll
  for (int mt = 0; mt < 4; ++mt) {
    accA[mt] = (f32x4){0.f, 0.f, 0.f, 0.f};
    accB[mt] = (f32x4){0.f, 0.f, 0.f, 0.f};
  }
  #pragma unroll
  for (int ks = 0; ks < 8; ++ks) {
    #pragma unroll
    for (int mt = 0; mt < 4; ++mt) {
      const int r = mt * 16 + cl;
      const int kb = (ks * 64 + krow * 2) ^ ((r & 7) << 4);
      const short8 af = *(const short8*)(lds + L_XT + r * 512 + kb);
      accA[mt] = __builtin_amdgcn_mfma_f32_16x16x32_bf16(af, wfA[ks], accA[mt], 0, 0, 0);
      accB[mt] = __builtin_amdgcn_mfma_f32_16x16x32_bf16(af, wfB[ks], accB[mt], 0, 0, 0);
    }
  }
  __syncthreads();   // all waves done reading Y before bounce overlays it

  // ---- epilogue: bias + relu -> per-wave bounce -> full 128B-line dwordx4 stores ----
  float* wb = (float*)(lds + L_XT) + w * (16 * 36);
  const int dA = w * 32 + cl;
  const float bvA = bias[dA], bvB = bias[dA + 16];
  #pragma unroll
  for (int mt = 0; mt < 4; ++mt) {
    #pragma unroll
    for (int q = 0; q < 4; ++q) {
      const int r16 = (lane >> 4) * 4 + q;
      const float rsv = rsl[mt * 16 + r16];
      wb[r16 * 36 + cl]      = fmaxf(accA[mt][q] + rsv * bvA, 0.f);
      wb[r16 * 36 + 16 + cl] = fmaxf(accB[mt][q] + rsv * bvB, 0.f);
    }
    asm volatile("s_waitcnt lgkmcnt(0)" ::: "memory");   // per-wave private region
    #pragma unroll
    for (int v = 0; v < 2; ++v) {
      const int i = lane * 2 + v;                        // 128 vec4 slots of 16x32 tile
      const int rI = i >> 3, cv = i & 7;
      const int n = n0 + mt * 16 + rI;
      if (n < NND)
        *(f32x4*)(out + ((size_t)bt * NND + n) * 256 + w * 32 + cv * 4) =
            *(const f32x4*)(wb + rI * 36 + cv * 4);
    }
  }
}

extern "C" void kernel_launch(void* const* d_in, const int* in_sizes, int n_in,
                              void* d_out, int out_size, void* d_ws, size_t ws_size,
                              hipStream_t stream) {
  const float* x  = (const float*)d_in[0];
  const float* Wm = (const float*)d_in[1];
  const float* b  = (const float*)d_in[2];
  const float* A  = (const float*)d_in[3];
  float* out = (float*)d_out;
  const int use_ws = (d_ws != nullptr && ws_size >= (size_t)WS_NEED) ? 1 : 0;
  if (use_ws) {
    prep_a<<<(NTILES * NCH * 8 * 64 + 255) / 256, 256, 0, stream>>>(A, (char*)d_ws);
    prep_w<<<(16 * 8 * 64 + 255) / 256, 256, 0, stream>>>(Wm, (char*)d_ws);
    prep_rs<<<(NTILES * RPB * 64 + 255) / 256, 256, 0, stream>>>(A, (char*)d_ws);
  }
  gcn_main<<<GRID, 512, 0, stream>>>(x, Wm, b, A, out, (const char*)d_ws, use_ws);
}

// Round 14
// 598.676 us; speedup vs baseline: 1.9260x; 1.9260x over previous
//
#include <hip/hip_runtime.h>
#include <hip/hip_bf16.h>

// GraphConvLayer: out = relu(A_norm @ (X@W + b))
// R14: dense two-GEMM (R12 skeleton) with X PREPACKED into MFMA B-fragment layout
// by a streaming prep kernel (bf16, ~302MB ws). Hot loop staging = 5x
// global_load_lds(16B) per chunk: no VALU, no transpose, conflict-free ds_read_b128.
//   GEMM1: Y[64][256] = A_tile[64][543] @ X_bt[543][256]   (K-chunks of 64)
//   GEMM2: out = relu(Y @ W + rowsum(A)*b)
// mode 2: big ws (Xf path) | mode 1: small ws (R12 in-kernel staging) | mode 0: bare.

#define NND    543
#define RPB    64
#define NTILES 9
#define NCH    9
#define BTOT   1024
#define GRID   (BTOT*NTILES)   // 9216, %8==0 -> bijective XCD swizzle

typedef __attribute__((ext_vector_type(8))) short short8;
typedef __attribute__((ext_vector_type(4))) float f32x4;

// ---- workspace ----
// mode 2: [ Xf : XF_BYTES ][ meta: A-frags | W-frags | RS ]
// mode 1: [ meta ... ] only
#define XF_BYTES ((size_t)BTOT*NCH*2048*16)   // 301,989,888: [bt][chunk][fg16*ks2*lane64][16B]
#define MT_A     0                            // bf16 A-frags [tile9][chunk9][f8][lane64][8] = 663552
#define MT_W     663552                       // bf16 W-frags [g16][ks8][lane64][8] = 131072
#define MT_RS    794624                       // f32[576] rowsum
#define MT_BYTES 797184
#define WS_BIG   (XF_BYTES + (size_t)MT_BYTES)
#define WS_SMALL ((size_t)MT_BYTES)

// ---- LDS (bytes), mode-2 main ----
#define L_XF   0            // X-frag chunk 32768; Y-swz [64][512B] overlays after GEMM1
#define L_A    32768        // A-frag chunk 8192
#define L_RS   40960        // f32[64]
#define L_TOT  41216

#define GLD16(G, Ld) __builtin_amdgcn_global_load_lds( \
    (const __attribute__((address_space(1))) void*)(G), \
    (__attribute__((address_space(3))) void*)(Ld), 16, 0, 0)

__device__ __forceinline__ unsigned short f2bf(float f) {   // RNE f32 -> bf16 bits
  unsigned int u = __builtin_bit_cast(unsigned int, f);
  u += 0x7fffu + ((u >> 16) & 1u);
  return (unsigned short)(u >> 16);
}

// ---------------- prep: X -> bf16 B-fragment layout (one block per (bt,chunk)) ----------------
// frag fi = (fg*2+ks)*64+lane ; elem e: k = ks*32+(lane>>4)*8+e (row within chunk),
//                                       n = fg*16+(lane&15) (feature)
__global__ void prep_xf(const float* __restrict__ x, char* __restrict__ xf) {
  __shared__ __align__(16) char xl[64 * 512];          // bf16 [64 rows][256 f]
  const int bc = blockIdx.x;                           // bt*NCH + c
  const int bt = bc / NCH, c = bc - bt * NCH;
  const int tid = threadIdx.x;                         // 256
  const float* xbt = x + (size_t)bt * (NND * 256);
  #pragma unroll
  for (int it = 0; it < 16; ++it) {
    const int slot = tid + (it << 8);                  // 4096 float4 slots
    const int r = slot >> 6, f4 = slot & 63;
    const int m = c * 64 + r;
    float4 v = make_float4(0.f, 0.f, 0.f, 0.f);
    if (m < NND) v = *(const float4*)(xbt + ((size_t)m << 8) + (f4 << 2));
    uint2 u;
    u.x = (unsigned)f2bf(v.x) | ((unsigned)f2bf(v.y) << 16);
    u.y = (unsigned)f2bf(v.z) | ((unsigned)f2bf(v.w) << 16);
    *(uint2*)(xl + (r << 9) + (f4 << 3)) = u;
  }
  __syncthreads();
  unsigned short* dst = (unsigned short*)xf + ((size_t)bc << 14);   // 2048 frags * 8 u16
  const unsigned short* src = (const unsigned short*)xl;
  #pragma unroll
  for (int it = 0; it < 8; ++it) {
    const int fi = tid + (it << 8);
    const int lane = fi & 63, ks = (fi >> 6) & 1, fg = fi >> 7;
    const int kl = ks * 32 + (lane >> 4) * 8;
    const int n = fg * 16 + (lane & 15);
    unsigned short tmp[8];
    #pragma unroll
    for (int e = 0; e < 8; ++e) tmp[e] = src[(kl + e) * 256 + n];
    *(uint4*)(dst + (size_t)fi * 8) = *(const uint4*)tmp;
  }
}

// ---------------- prep: A -> bf16 MFMA A-fragments (meta base) ----------------
__global__ void prep_a(const float* __restrict__ A, char* __restrict__ meta) {
  const int t = blockIdx.x * 256 + threadIdx.x;
  if (t >= NTILES * NCH * 8 * 64) return;
  const int lane = t & 63;
  const int f = (t >> 6) & 7;
  const int c = (t >> 9) % NCH;
  const int tile = t / (NCH * 8 * 64);
  const int mt = f >> 1, ks = f & 1;
  const int m = tile * 64 + mt * 16 + (lane & 15);
  const int kb = c * 64 + ks * 32 + (lane >> 4) * 8;
  unsigned short* dst = (unsigned short*)(meta + MT_A) + (size_t)t * 8;
  #pragma unroll
  for (int e = 0; e < 8; ++e) {
    const int k = kb + e;
    dst[e] = (m < NND && k < NND) ? f2bf(A[(size_t)m * NND + k]) : (unsigned short)0;
  }
}

// ---------------- prep: W -> bf16 MFMA B-fragments ----------------
__global__ void prep_w(const float* __restrict__ W, char* __restrict__ meta) {
  const int t = blockIdx.x * 256 + threadIdx.x;
  if (t >= 16 * 8 * 64) return;
  const int lane = t & 63, ks = (t >> 6) & 7, g = t >> 9;
  const int krow = (lane >> 4) * 8, col = g * 16 + (lane & 15);
  unsigned short* dst = (unsigned short*)(meta + MT_W) + (size_t)t * 8;
  #pragma unroll
  for (int e = 0; e < 8; e++) dst[e] = f2bf(W[(ks * 32 + krow + e) * 256 + col]);
}

// ---------------- prep: rowsum ----------------
__global__ void prep_rs(const float* __restrict__ A, char* __restrict__ meta) {
  const int wid = (blockIdx.x * blockDim.x + threadIdx.x) >> 6;
  const int lane = threadIdx.x & 63;
  if (wid >= NTILES * RPB) return;
  float s = 0.f;
  if (wid < NND) {
    const float* arow = A + (size_t)wid * NND;
    for (int m = lane; m < NND; m += 64) s += arow[m];
  }
  #pragma unroll
  for (int o = 32; o > 0; o >>= 1) s += __shfl_xor(s, o);
  if (lane == 0) ((float*)(meta + MT_RS))[wid] = s;
}

// ---------------- main ----------------
__global__ __launch_bounds__(512, 2)
void gcn_main(const float* __restrict__ x, const float* __restrict__ Wm,
              const float* __restrict__ bias, const float* __restrict__ A,
              float* __restrict__ out, const char* __restrict__ xfb,
              const char* __restrict__ meta, int mode)
{
  __shared__ __align__(16) char lds[L_TOT];
  float* rsl = (float*)(lds + L_RS);

  const int tid = threadIdx.x;
  const int w = tid >> 6, lane = tid & 63;
  const int cl = lane & 15, krow = (lane >> 4) * 8;

  const int p = blockIdx.x;
  const int L = (p & 7) * (GRID / 8) + (p >> 3);
  const int bt = L / NTILES;
  const int tile = L - bt * NTILES;
  const int n0 = tile * RPB;

  const float* xbt = x + (size_t)bt * (NND * 256);

  if (mode >= 1 && tid < RPB) rsl[tid] = ((const float*)(meta + MT_RS))[n0 + tid];

  if (mode == 2) {
    // ======== GEMM1 (frag path): staging = global_load_lds only ========
    f32x4 acc[8];
    #pragma unroll
    for (int i = 0; i < 8; ++i) acc[i] = (f32x4){0.f, 0.f, 0.f, 0.f};

    for (int c = 0; c < NCH; ++c) {
      __builtin_amdgcn_s_barrier();                    // all waves done reading prev chunk
      const char* xsrc = xfb + (((size_t)(bt * NCH + c)) << 15);
      #pragma unroll
      for (int i = 0; i < 4; ++i) {                    // 4 x 1KB X-frag slices per wave
        const int s = (w << 2) + i;
        GLD16(xsrc + (s << 10) + (lane << 4), lds + L_XF + (s << 10));
      }
      GLD16(meta + MT_A + (((size_t)(tile * NCH + c)) << 13) + (w << 10) + (lane << 4),
            lds + L_A + (w << 10));
      asm volatile("s_waitcnt vmcnt(0)" ::: "memory");
      __builtin_amdgcn_s_barrier();
      __builtin_amdgcn_sched_barrier(0);

      #pragma unroll
      for (int ks = 0; ks < 2; ++ks) {
        short8 af[4], xff[2];
        #pragma unroll
        for (int mt = 0; mt < 4; ++mt)
          af[mt] = *(const short8*)(lds + L_A + (((mt * 2 + ks) * 64 + lane) << 4));
        #pragma unroll
        for (int nt = 0; nt < 2; ++nt) {
          const int fg = w * 2 + nt;
          xff[nt] = *(const short8*)(lds + L_XF + (((fg * 2 + ks) * 64 + lane) << 4));
        }
        #pragma unroll
        for (int mt = 0; mt < 4; ++mt)
          #pragma unroll
          for (int nt = 0; nt < 2; ++nt)
            acc[mt * 2 + nt] =
                __builtin_amdgcn_mfma_f32_16x16x32_bf16(af[mt], xff[nt], acc[mt * 2 + nt], 0, 0, 0);
      }
    }
    // Y -> LDS bf16 [64][512B] XOR-swz (overlays X-frag buffer)
    __syncthreads();
    #pragma unroll
    for (int mt = 0; mt < 4; ++mt)
      #pragma unroll
      for (int nt = 0; nt < 2; ++nt)
        #pragma unroll
        for (int q = 0; q < 4; ++q) {
          const int row = mt * 16 + (lane >> 4) * 4 + q;   // C/D: col=lane&15, row=(lane>>4)*4+q
          const int col = w * 32 + nt * 16 + cl;
          *(unsigned short*)(lds + L_XF + row * 512 + ((col * 2) ^ ((row & 7) << 4))) =
              f2bf(acc[mt * 2 + nt][q]);
        }
  } else if (mode == 1) {
    // ======== GEMM1 (R12 path): in-kernel transposed staging ========
    f32x4 acc[8];
    #pragma unroll
    for (int i = 0; i < 8; ++i) acc[i] = (f32x4){0.f, 0.f, 0.f, 0.f};
    for (int c = 0; c < NCH; ++c) {
      const int kv = min(64, NND - c * 64);
      __syncthreads();
      #pragma unroll 2
      for (int it = 0; it < 8; ++it) {
        const int s = tid + (it << 9);
        const int n = s & 255, k0 = (s >> 8) * 4;
        float v0 = 0.f, v1 = 0.f, v2 = 0.f, v3 = 0.f;
        if (k0 + 0 < kv) v0 = xbt[(c * 64 + k0 + 0) * 256 + n];
        if (k0 + 1 < kv) v1 = xbt[(c * 64 + k0 + 1) * 256 + n];
        if (k0 + 2 < kv) v2 = xbt[(c * 64 + k0 + 2) * 256 + n];
        if (k0 + 3 < kv) v3 = xbt[(c * 64 + k0 + 3) * 256 + n];
        uint2 u;
        u.x = (unsigned)f2bf(v0) | ((unsigned)f2bf(v1) << 16);
        u.y = (unsigned)f2bf(v2) | ((unsigned)f2bf(v3) << 16);
        *(uint2*)(lds + L_XF + n * 128 + ((k0 * 2) ^ ((n & 7) << 4))) = u;
      }
      *(uint4*)(lds + L_A + (tid << 4)) =
          *(const uint4*)(meta + MT_A + ((size_t)((tile * NCH + c) * 512 + tid) << 4));
      __syncthreads();
      #pragma unroll
      for (int ks = 0; ks < 2; ++ks) {
        short8 af[4], xff[2];
        #pragma unroll
        for (int mt = 0; mt < 4; ++mt)
          af[mt] = *(const short8*)(lds + L_A + (((mt * 2 + ks) * 64 + lane) << 4));
        #pragma unroll
        for (int nt = 0; nt < 2; ++nt) {
          const int n = w * 32 + nt * 16 + cl;
          xff[nt] = *(const short8*)(lds + L_XF + n * 128 +
                                     (((ks * 32 + krow) * 2) ^ ((n & 7) << 4)));
        }
        #pragma unroll
        for (int mt = 0; mt < 4; ++mt)
          #pragma unroll
          for (int nt = 0; nt < 2; ++nt)
            acc[mt * 2 + nt] =
                __builtin_amdgcn_mfma_f32_16x16x32_bf16(af[mt], xff[nt], acc[mt * 2 + nt], 0, 0, 0);
      }
    }
    __syncthreads();
    #pragma unroll
    for (int mt = 0; mt < 4; ++mt)
      #pragma unroll
      for (int nt = 0; nt < 2; ++nt)
        #pragma unroll
        for (int q = 0; q < 4; ++q) {
          const int row = mt * 16 + (lane >> 4) * 4 + q;
          const int col = w * 32 + nt * 16 + cl;
          *(unsigned short*)(lds + L_XF + row * 512 + ((col * 2) ^ ((row & 7) << 4))) =
              f2bf(acc[mt * 2 + nt][q]);
        }
  } else {
    // ---- bare fallback: dense per-row f32 gather + rowsum ----
    for (int i = 0; i < 8; ++i) {
      const int r = w * 8 + i;
      const int n = n0 + r;
      f32x4 yv = (f32x4){0.f, 0.f, 0.f, 0.f};
      float s = 0.f;
      if (n < NND) {
        const float* arow = A + (size_t)n * NND;
        for (int m = 0; m < NND; ++m) {
          const float a = arow[m];
          s += a;
          if (a != 0.f) yv += a * *(const f32x4*)(xbt + (m << 8) + (lane << 2));
        }
      }
      if (lane == 0) rsl[r] = s;
      uint2 u;
      u.x = (unsigned)f2bf(yv.x) | ((unsigned)f2bf(yv.y) << 16);
      u.y = (unsigned)f2bf(yv.z) | ((unsigned)f2bf(yv.w) << 16);
      *(uint2*)(lds + L_XF + r * 512 + ((lane * 8) ^ ((r & 7) << 4))) = u;
    }
  }
  __syncthreads();

  // ======== GEMM2: out_tile = relu(Y@W + rs*b); wave w owns cols [w*32, w*32+32) ========
  const int gA = 2 * w;
  short8 wfA[8], wfB[8];
  if (mode >= 1) {
    #pragma unroll
    for (int ks = 0; ks < 8; ++ks) {
      wfA[ks] = *(const short8*)(meta + MT_W + (size_t)(((gA * 8 + ks) * 64 + lane) << 4));
      wfB[ks] = *(const short8*)(meta + MT_W + (size_t)((((gA + 1) * 8 + ks) * 64 + lane) << 4));
    }
  } else {
    #pragma unroll
    for (int ks = 0; ks < 8; ++ks) {
      #pragma unroll
      for (int e = 0; e < 8; ++e) {
        wfA[ks][e] = (short)f2bf(Wm[(ks * 32 + krow + e) * 256 + gA * 16 + cl]);
        wfB[ks][e] = (short)f2bf(Wm[(ks * 32 + krow + e) * 256 + (gA + 1) * 16 + cl]);
      }
    }
  }
  f32x4 accA[4], accB[4];
  #pragma unroll
  for (int mt = 0; mt < 4; ++mt) {
    accA[mt] = (f32x4){0.f, 0.f, 0.f, 0.f};
    accB[mt] = (f32x4){0.f, 0.f, 0.f, 0.f};
  }
  #pragma unroll
  for (int ks = 0; ks < 8; ++ks) {
    #pragma unroll
    for (int mt = 0; mt < 4; ++mt) {
      const int r = mt * 16 + cl;
      const int kb = (ks * 64 + krow * 2) ^ ((r & 7) << 4);
      const short8 af = *(const short8*)(lds + L_XF + r * 512 + kb);
      accA[mt] = __builtin_amdgcn_mfma_f32_16x16x32_bf16(af, wfA[ks], accA[mt], 0, 0, 0);
      accB[mt] = __builtin_amdgcn_mfma_f32_16x16x32_bf16(af, wfB[ks], accB[mt], 0, 0, 0);
    }
  }
  __syncthreads();   // all waves done reading Y before bounce overlays it

  // ---- epilogue: bias + relu -> per-wave bounce -> full 128B-line dwordx4 stores ----
  float* wb = (float*)(lds + L_XF) + w * (16 * 36);
  const int dA = w * 32 + cl;
  const float bvA = bias[dA], bvB = bias[dA + 16];
  #pragma unroll
  for (int mt = 0; mt < 4; ++mt) {
    #pragma unroll
    for (int q = 0; q < 4; ++q) {
      const int r16 = (lane >> 4) * 4 + q;
      const float rsv = rsl[mt * 16 + r16];
      wb[r16 * 36 + cl]      = fmaxf(accA[mt][q] + rsv * bvA, 0.f);
      wb[r16 * 36 + 16 + cl] = fmaxf(accB[mt][q] + rsv * bvB, 0.f);
    }
    asm volatile("s_waitcnt lgkmcnt(0)" ::: "memory");   // per-wave private region
    #pragma unroll
    for (int v = 0; v < 2; ++v) {
      const int i = lane * 2 + v;
      const int rI = i >> 3, cv = i & 7;
      const int n = n0 + mt * 16 + rI;
      if (n < NND)
        *(f32x4*)(out + ((size_t)bt * NND + n) * 256 + w * 32 + cv * 4) =
            *(const f32x4*)(wb + rI * 36 + cv * 4);
    }
  }
}

extern "C" void kernel_launch(void* const* d_in, const int* in_sizes, int n_in,
                              void* d_out, int out_size, void* d_ws, size_t ws_size,
                              hipStream_t stream) {
  const float* x  = (const float*)d_in[0];
  const float* Wm = (const float*)d_in[1];
  const float* b  = (const float*)d_in[2];
  const float* A  = (const float*)d_in[3];
  float* out = (float*)d_out;
  const int mode = (d_ws && ws_size >= WS_BIG) ? 2
                 : (d_ws && ws_size >= WS_SMALL) ? 1 : 0;
  char* xfp  = (char*)d_ws;
  char* meta = (char*)d_ws + (mode == 2 ? XF_BYTES : 0);
  if (mode >= 1) {
    prep_a<<<(NTILES * NCH * 8 * 64 + 255) / 256, 256, 0, stream>>>(A, meta);
    prep_w<<<(16 * 8 * 64 + 255) / 256, 256, 0, stream>>>(Wm, meta);
    prep_rs<<<(NTILES * RPB * 64 + 255) / 256, 256, 0, stream>>>(A, meta);
    if (mode == 2) prep_xf<<<BTOT * NCH, 256, 0, stream>>>(x, xfp);
  }
  gcn_main<<<GRID, 512, 0, stream>>>(x, Wm, b, A, out, xfp, meta, mode);
}